// Round 9
// baseline (555.237 us; speedup 1.0000x reference)
//
#include <hip/hip_runtime.h>
#include <hip/hip_bf16.h>
#include <stdint.h>

// Match numpy/XLA elementwise rounding: no FMA contraction anywhere in ref math.
#pragma clang fp contract(off)

#define BS 4
#define NQ 900
#define NC 1203
#define NCAND (NQ*NC)      // 1082700
#define N4 (NCAND/4)       // 270675 (exact)
#define TOPK 10000
#define SSEL 300
#define CAP 16384
#define ECAP 65536
#define TARGET 10240       // top-k margin over 10000 for sigmoid tie-groups
#define SEGLEN 256         // rank: keys per LDS segment (fixed-trip, zero-padded)
#define IPT 16             // rank: i-keys per thread (ILP depth)
#define IPB (256*IPT)      // 4096 i-keys per block

struct WSHead {                       // zero-initialized via one memset
  uint32_t ghist1[BS][4096];
  uint32_t ghist2[BS][4096];
  uint32_t rnk[BS][CAP];              // partial rank counts (zeroed)
  uint32_t compCnt[BS];
  uint32_t B12v[BS];
  uint32_t cntAbove[BS];
  uint32_t Tkey[BS];
  uint32_t pad[64];
};
struct WSBody {                       // fully overwritten before any read
  uint64_t skey[BS][CAP];
  float    srtS[BS][TOPK];
  float    bx4[BS][TOPK][4];
  int32_t  lab[BS][TOPK];
  float    x1o[BS][TOPK];
  float    y1o[BS][TOPK];
  float    x2o[BS][TOPK];
  float    y2o[BS][TOPK];
  float    areaA[BS][TOPK];
  uint32_t entry[BS][TOPK];
  uint32_t eI[BS][ECAP];
  uint32_t eJ[BS][ECAP];
};
struct WS { WSHead h; WSBody bd; };

__device__ __forceinline__ uint32_t ordkey(float f){
  uint32_t u = __float_as_uint(f);
  return u ^ ((u & 0x80000000u) ? 0xFFFFFFFFu : 0x80000000u);
}
__device__ __forceinline__ float invord(uint32_t k){
  uint32_t u = (k & 0x80000000u) ? (k ^ 0x80000000u) : ~k;
  return __uint_as_float(u);
}

// XLA:CPU-style Cephes expf — verified bit-exact (absmax 0.0). DO NOT TOUCH.
__device__ __forceinline__ float ref_expf(float x){
  float xc = fminf(fmaxf(x, -87.3365478515625f), 88.3762626647949f);
  float fx = floorf(fmaf(xc, 1.44269504088896341f, 0.5f));
  float r  = fmaf(fx, -0.693359375f, xc);
  r = fmaf(fx, 2.12194440e-4f, r);
  float r2 = r*r;
  float y = fmaf(1.9875691500E-4f, r, 1.3981999507E-3f);
  y = fmaf(y, r, 8.3334519073E-3f);
  y = fmaf(y, r, 4.1665795894E-2f);
  y = fmaf(y, r, 1.6666665459E-1f);
  y = fmaf(y, r, 5.0000001201E-1f);
  y = fmaf(y, r2, r);
  y = y + 1.0f;
  float p2n = __uint_as_float((uint32_t)(((int)fx + 127) << 23));
  return y * p2n;
}
__device__ __forceinline__ float ref_sigmoid(float x){
  return 1.0f / (1.0f + ref_expf(-x));
}

// ---------------- pass 1: coarse 12-bit histogram of ordered logit keys ----
__global__ void k_hist1(const float4* __restrict__ L, WS* w){
  int b = blockIdx.y;
  __shared__ uint32_t h[4096];
  for (int i = threadIdx.x; i < 4096; i += blockDim.x) h[i] = 0;
  __syncthreads();
  const float4* Lb = L + (size_t)b * N4;
  for (int i = blockIdx.x*blockDim.x + threadIdx.x; i < N4; i += gridDim.x*blockDim.x){
    float4 v = Lb[i];
    atomicAdd(&h[ordkey(v.x)>>20], 1u);
    atomicAdd(&h[ordkey(v.y)>>20], 1u);
    atomicAdd(&h[ordkey(v.z)>>20], 1u);
    atomicAdd(&h[ordkey(v.w)>>20], 1u);
  }
  __syncthreads();
  for (int i = threadIdx.x; i < 4096; i += blockDim.x){
    uint32_t c = h[i];
    if (c) atomicAdd(&w->h.ghist1[b][i], c);   // no return value -> fire-and-forget
  }
}

// parallel suffix-scan selection: B12 = max bin with suffixInc(bin) >= TARGET
__global__ void __launch_bounds__(1024) k_sel1(WS* w){
  int b = blockIdx.x;
  int t = threadIdx.x;
  __shared__ uint32_t ts[1024];
  uint32_t v0 = w->h.ghist1[b][4*t+0];
  uint32_t v1 = w->h.ghist1[b][4*t+1];
  uint32_t v2 = w->h.ghist1[b][4*t+2];
  uint32_t v3 = w->h.ghist1[b][4*t+3];
  uint32_t mysum = v0+v1+v2+v3;
  ts[t] = mysum;
  __syncthreads();
  for (int off = 1; off < 1024; off <<= 1){       // inclusive SUFFIX scan
    uint32_t add = (t + off < 1024) ? ts[t + off] : 0;
    __syncthreads();
    ts[t] += add;
    __syncthreads();
  }
  uint32_t above = (t < 1023) ? ts[t+1] : 0;      // sum of bins >= 4(t+1)
  uint32_t si3 = v3 + above;
  uint32_t si2 = v2 + si3;
  uint32_t si1 = v1 + si2;
  uint32_t si0 = v0 + si1;
  if (si3 >= TARGET && above < TARGET){ w->h.B12v[b] = 4*t+3; w->h.cntAbove[b] = above; }
  if (si2 >= TARGET && si3   < TARGET){ w->h.B12v[b] = 4*t+2; w->h.cntAbove[b] = si3; }
  if (si1 >= TARGET && si2   < TARGET){ w->h.B12v[b] = 4*t+1; w->h.cntAbove[b] = si2; }
  if (si0 >= TARGET && si1   < TARGET){ w->h.B12v[b] = 4*t+0; w->h.cntAbove[b] = si1; }
}

// ---------------- pass 2: refine within boundary bucket (next 12 bits) -----
__global__ void k_hist2(const float4* __restrict__ L, WS* w){
  int b = blockIdx.y;
  uint32_t B = w->h.B12v[b];
  const float4* Lb = L + (size_t)b * N4;
  for (int i = blockIdx.x*blockDim.x + threadIdx.x; i < N4; i += gridDim.x*blockDim.x){
    float4 v = Lb[i];
    uint32_t k;
    k = ordkey(v.x); if ((k>>20) == B) atomicAdd(&w->h.ghist2[b][(k>>8)&0xFFFu], 1u);
    k = ordkey(v.y); if ((k>>20) == B) atomicAdd(&w->h.ghist2[b][(k>>8)&0xFFFu], 1u);
    k = ordkey(v.z); if ((k>>20) == B) atomicAdd(&w->h.ghist2[b][(k>>8)&0xFFFu], 1u);
    k = ordkey(v.w); if ((k>>20) == B) atomicAdd(&w->h.ghist2[b][(k>>8)&0xFFFu], 1u);
  }
}

__global__ void __launch_bounds__(1024) k_sel2(WS* w){
  int b = blockIdx.x;
  int t = threadIdx.x;
  uint32_t A = w->h.cntAbove[b];
  uint32_t B = w->h.B12v[b];
  __shared__ uint32_t ts[1024];
  uint32_t v0 = w->h.ghist2[b][4*t+0];
  uint32_t v1 = w->h.ghist2[b][4*t+1];
  uint32_t v2 = w->h.ghist2[b][4*t+2];
  uint32_t v3 = w->h.ghist2[b][4*t+3];
  uint32_t mysum = v0+v1+v2+v3;
  ts[t] = mysum;
  __syncthreads();
  for (int off = 1; off < 1024; off <<= 1){       // inclusive SUFFIX scan
    uint32_t add = (t + off < 1024) ? ts[t + off] : 0;
    __syncthreads();
    ts[t] += add;
    __syncthreads();
  }
  uint32_t above = (t < 1023) ? ts[t+1] : 0;
  uint32_t si3 = v3 + above;
  uint32_t si2 = v2 + si3;
  uint32_t si1 = v1 + si2;
  uint32_t si0 = v0 + si1;
  if (A + si3 >= TARGET && A + above < TARGET) w->h.Tkey[b] = (B<<20) | ((uint32_t)(4*t+3)<<8);
  if (A + si2 >= TARGET && A + si3   < TARGET) w->h.Tkey[b] = (B<<20) | ((uint32_t)(4*t+2)<<8);
  if (A + si1 >= TARGET && A + si2   < TARGET) w->h.Tkey[b] = (B<<20) | ((uint32_t)(4*t+1)<<8);
  if (A + si0 >= TARGET && A + si1   < TARGET) w->h.Tkey[b] = (B<<20) | ((uint32_t)(4*t+0)<<8);
}

// ---------------- pass 3: SINGLE-sweep compaction via LDS staging ----------
// Passing candidates collect in a 2048-entry LDS buffer (expected ~80/block,
// 100-sigma bound << 2048); ONE global atomic per block reserves the output
// range; bulk copy follows. Correct spill path for the impossible overflow.
// Emission order is irrelevant downstream (rankp sorts by value).
__global__ void k_compact(const float4* __restrict__ L, WS* w){
  int b = blockIdx.y;
  uint32_t T = w->h.Tkey[b];
  const float4* Lb = L + (size_t)b * N4;
  __shared__ uint64_t buf[2048];
  __shared__ uint32_t lcnt, gbase;
  if (threadIdx.x == 0) lcnt = 0;
  __syncthreads();
  for (int i = blockIdx.x*blockDim.x + threadIdx.x; i < N4; i += gridDim.x*blockDim.x){
    float4 v = Lb[i];
    float c4[4] = {v.x, v.y, v.z, v.w};
    #pragma unroll
    for (int c = 0; c < 4; ++c){
      uint32_t k = ordkey(c4[c]);
      if (k >= T){
        float s = ref_sigmoid(c4[c]);
        uint32_t idx = (uint32_t)(i*4 + c);
        uint64_t key = ((uint64_t)__float_as_uint(s) << 32) | (uint32_t)(~idx);
        uint32_t p = atomicAdd(&lcnt, 1u);         // LDS atomic (fast)
        if (p < 2048u) buf[p] = key;
        else {                                     // spill (never in practice)
          uint32_t g = atomicAdd(&w->h.compCnt[b], 1u);
          if (g < CAP) w->bd.skey[b][g] = key;
        }
      }
    }
  }
  __syncthreads();
  uint32_t n = lcnt; if (n > 2048u) n = 2048u;
  if (threadIdx.x == 0) gbase = (n > 0) ? atomicAdd(&w->h.compCnt[b], n) : 0;
  __syncthreads();
  for (uint32_t u = threadIdx.x; u < n; u += blockDim.x){
    uint32_t g = gbase + u;
    if (g < CAP) w->bd.skey[b][g] = buf[u];
  }
}

// O(C^2) rank via 2-D (i-chunk x key-segment) partial counts.
// IPT=16 i-keys/thread: each LDS broadcast read feeds 16 compares -> LDS
// latency amortized 2x vs round 8. Fixed-trip zero-padded tile (pad key 0 <
// every real key since sigmoid bits > 0 -> counts exact).
__global__ void __launch_bounds__(256) k_rankp(WS* w){
  int b = blockIdx.z;
  uint32_t C = w->h.compCnt[b]; if (C > CAP) C = CAP;
  uint32_t i0 = blockIdx.x * IPB;
  uint32_t s0 = blockIdx.y * SEGLEN;
  if (i0 >= C || s0 >= C) return;            // uniform whole-block exit
  const uint64_t* __restrict__ K = w->bd.skey[b];
  __shared__ uint64_t tile[SEGLEN];
  tile[threadIdx.x] = (s0 + threadIdx.x < C) ? K[s0 + threadIdx.x] : 0ull;
  uint64_t mine[IPT];
  uint32_t cnt[IPT];
  #pragma unroll
  for (int k = 0; k < IPT; ++k){
    uint32_t i = i0 + k*256u + threadIdx.x;
    mine[k] = (i < C) ? K[i] : ~0ull;        // sentinel lanes never flush
    cnt[k] = 0;
  }
  __syncthreads();
  for (uint32_t u = 0; u < SEGLEN; u += 8){
    uint64_t t0 = tile[u  ], t1 = tile[u+1], t2 = tile[u+2], t3 = tile[u+3];
    uint64_t t4 = tile[u+4], t5 = tile[u+5], t6 = tile[u+6], t7 = tile[u+7];
    #pragma unroll
    for (int k = 0; k < IPT; ++k)
      cnt[k] += (uint32_t)(t0 > mine[k]) + (uint32_t)(t1 > mine[k])
              + (uint32_t)(t2 > mine[k]) + (uint32_t)(t3 > mine[k])
              + (uint32_t)(t4 > mine[k]) + (uint32_t)(t5 > mine[k])
              + (uint32_t)(t6 > mine[k]) + (uint32_t)(t7 > mine[k]);
  }
  #pragma unroll
  for (int k = 0; k < IPT; ++k){
    uint32_t i = i0 + k*256u + threadIdx.x;
    if (i < C && cnt[k]) atomicAdd(&w->h.rnk[b][i], cnt[k]);
  }
}

// ---------------- merged tail: pg + cstart + os + edges + NMS + out --------
// One block per batch; phases separated by block barriers (all per-batch
// state is touched only by this block; __syncthreads orders global+LDS).
__global__ void __launch_bounds__(1024) k_tail(WS* __restrict__ w,
                    const float* __restrict__ pboxes,
                    const float* __restrict__ tsz,
                    float* __restrict__ out){
  int b = blockIdx.x;
  int tid = threadIdx.x;
  __shared__ uint32_t ccnt[NC];
  __shared__ uint32_t cfill[NC];
  __shared__ uint32_t cstart[NC+1];
  __shared__ uint32_t ts[1024];
  __shared__ uint8_t keep[TOPK];
  __shared__ uint8_t supp[TOPK];
  __shared__ uint32_t ps[1024];
  __shared__ int changed;
  __shared__ uint32_t ecnt_l;
  __shared__ float sh_maxc, sh_minc;

  // ---- phase A: place+gather by final rank; label counts; extrema ----
  for (int c = tid; c < NC; c += 1024){ ccnt[c] = 0; cfill[c] = 0; }
  if (tid == 0) ecnt_l = 0;
  __syncthreads();
  uint32_t C = w->h.compCnt[b]; if (C > CAP) C = CAP;
  uint32_t mo = 0, mno = 0;
  for (uint32_t i = tid; i < CAP; i += 1024u){
    if (i < C){
      uint32_t r = w->h.rnk[b][i];
      if (r < TOPK){
        uint64_t key = w->bd.skey[b][i];
        uint32_t idx = ~(uint32_t)key;
        uint32_t q = idx / NC;
        uint32_t c = idx - q*NC;
        const float* pb = pboxes + ((size_t)b*NQ + q)*4;
        float cx = pb[0], cy = pb[1], bw = pb[2], bh = pb[3];
        float hw = 0.5f*bw, hh = 0.5f*bh;
        float x1 = cx - hw, y1 = cy - hh, x2 = cx + hw, y2 = cy + hh;
        float ihh = tsz[b*2 + 0], iww = tsz[b*2 + 1];
        float b0 = x1*iww, b1 = y1*ihh, b2 = x2*iww, b3 = y2*ihh;
        w->bd.bx4[b][r][0] = b0; w->bd.bx4[b][r][1] = b1;
        w->bd.bx4[b][r][2] = b2; w->bd.bx4[b][r][3] = b3;
        w->bd.lab[b][r] = (int)c;
        w->bd.srtS[b][r] = __uint_as_float((uint32_t)(key >> 32));
        atomicAdd(&ccnt[c], 1u);
        float mx = fmaxf(fmaxf(b0,b1), fmaxf(b2,b3));
        float mn = fminf(fminf(b0,b1), fminf(b2,b3));
        uint32_t o1 = ordkey(mx), o2 = ~ordkey(mn);
        mo  = mo  > o1 ? mo  : o1;
        mno = mno > o2 ? mno : o2;
      }
    }
  }
  ts[tid] = mo; __syncthreads();
  for (int off = 512; off; off >>= 1){
    if (tid < off){ uint32_t a = ts[tid+off]; if (a > ts[tid]) ts[tid] = a; }
    __syncthreads();
  }
  if (tid == 0) sh_maxc = invord(ts[0]);
  __syncthreads();
  ts[tid] = mno; __syncthreads();
  for (int off = 512; off; off >>= 1){
    if (tid < off){ uint32_t a = ts[tid+off]; if (a > ts[tid]) ts[tid] = a; }
    __syncthreads();
  }
  if (tid == 0) sh_minc = invord(~ts[0]);
  __syncthreads();

  // ---- phase B: class-start exclusive prefix scan (1203 counts) ------
  {
    uint32_t v0 = (2*tid   < NC) ? ccnt[2*tid]   : 0;
    uint32_t v1 = (2*tid+1 < NC) ? ccnt[2*tid+1] : 0;
    uint32_t mysum = v0 + v1;
    ts[tid] = mysum; __syncthreads();
    for (int off = 1; off < 1024; off <<= 1){
      uint32_t add = (tid >= off) ? ts[tid - off] : 0;
      __syncthreads(); ts[tid] += add; __syncthreads();
    }
    uint32_t base = ts[tid] - mysum;
    if (2*tid   <= NC) cstart[2*tid]   = base;
    if (2*tid+1 <= NC) cstart[2*tid+1] = base + v0;
  }
  __syncthreads();

  // ---- phase C: offset boxes (ref-exact) + class-bucket scatter ------
  {
    float maxc = sh_maxc;
    float M = maxc + 1.0f;
    for (int r = tid; r < TOPK; r += 1024){
      int c = w->bd.lab[b][r];
      float off = (float)c * M;
      float x1 = w->bd.bx4[b][r][0] + off;
      float y1 = w->bd.bx4[b][r][1] + off;
      float x2 = w->bd.bx4[b][r][2] + off;
      float y2 = w->bd.bx4[b][r][3] + off;
      float area = (x2 - x1) * (y2 - y1);
      w->bd.x1o[b][r] = x1; w->bd.y1o[b][r] = y1;
      w->bd.x2o[b][r] = x2; w->bd.y2o[b][r] = y2;
      w->bd.areaA[b][r] = area;
      uint32_t pos = cstart[c] + atomicAdd(&cfill[c], 1u);
      w->bd.entry[b][pos] = (uint32_t)r;
    }
  }
  __syncthreads();

  // ---- phase D: conflict edges (class window provably covers IoU>0) --
  {
    float maxc = sh_maxc, minc = sh_minc;
    float M = maxc + 1.0f;
    float span = maxc - minc;
    int D;
    if (M > 0.0f){ D = (int)floorf(span / M); if (D < 0) D = 0; if (D > NC-1) D = NC-1; }
    else D = NC-1;
    for (int j = tid; j < TOPK; j += 1024){
      int cj = w->bd.lab[b][j];
      float X1 = w->bd.x1o[b][j], Y1 = w->bd.y1o[b][j];
      float X2 = w->bd.x2o[b][j], Y2 = w->bd.y2o[b][j];
      float A  = w->bd.areaA[b][j];
      int c0 = cj - D; if (c0 < 0) c0 = 0;
      int c1 = cj + D; if (c1 > NC-1) c1 = NC-1;
      for (int cc = c0; cc <= c1; ++cc){
        uint32_t t0 = cstart[cc], t1 = cstart[cc+1];
        for (uint32_t t = t0; t < t1; ++t){
          uint32_t i = w->bd.entry[b][t];
          if (i >= (uint32_t)j) continue;
          float iw = fminf(w->bd.x2o[b][i], X2) - fmaxf(w->bd.x1o[b][i], X1);
          iw = fmaxf(iw, 0.0f);
          float ih = fminf(w->bd.y2o[b][i], Y2) - fmaxf(w->bd.y1o[b][i], Y1);
          ih = fmaxf(ih, 0.0f);
          float inter = iw * ih;
          float den = (w->bd.areaA[b][i] + A) - inter;
          float iou = inter / den;        // NaN (0/0) compares false, like numpy
          if (iou > 0.7f){
            uint32_t n = atomicAdd(&ecnt_l, 1u);
            if (n < ECAP){ w->bd.eI[b][n] = i; w->bd.eJ[b][n] = (uint32_t)j; }
          }
        }
      }
    }
  }
  __syncthreads();

  // ---- phase E: fixpoint NMS (race-fixed convergence snapshot) -------
  {
    for (int r = tid; r < TOPK; r += 1024) keep[r] = 1;
    uint32_t E = ecnt_l; if (E > ECAP) E = ECAP;
    const uint32_t* ei = w->bd.eI[b];
    const uint32_t* ej = w->bd.eJ[b];
    for (int round = 0; round < 128; ++round){
      for (int r = tid; r < TOPK; r += 1024) supp[r] = 0;
      if (tid == 0) changed = 0;
      __syncthreads();
      for (uint32_t e = tid; e < E; e += 1024u)
        if (keep[ei[e]]) supp[ej[e]] = 1;
      __syncthreads();
      for (int r = tid; r < TOPK; r += 1024){
        uint8_t nk = (uint8_t)(1 - supp[r]);
        if (nk != keep[r]){ keep[r] = nk; changed = 1; }
      }
      __syncthreads();
      int ch = changed;          // uniform snapshot
      __syncthreads();           // all reads complete before next round's write
      if (!ch) break;            // uniform branch
    }
  }

  // ---- phase F: stable compaction of kept ranks -> first 300 slots ---
  {
    int r0 = tid * 10;
    uint32_t cnt = 0;
    for (int u = 0; u < 10; ++u){ int r = r0 + u; if (r < TOPK) cnt += keep[r]; }
    ps[tid] = cnt;
    __syncthreads();
    for (int off = 1; off < 1024; off <<= 1){
      uint32_t v = 0;
      if (tid >= off) v = ps[tid - off];
      __syncthreads();
      if (tid >= off) ps[tid] += v;
      __syncthreads();
    }
    uint32_t totalK = ps[1023];
    uint32_t p = ps[tid] - cnt;
    for (int u = 0; u < 10; ++u){
      int r = r0 + u; if (r >= TOPK) break;
      if (keep[r]){
        if (p < SSEL){
          int o = b*SSEL + (int)p;
          out[o*4 + 0] = w->bd.bx4[b][r][0];
          out[o*4 + 1] = w->bd.bx4[b][r][1];
          out[o*4 + 2] = w->bd.bx4[b][r][2];
          out[o*4 + 3] = w->bd.bx4[b][r][3];
          out[BS*SSEL*4 + o] = w->bd.srtS[b][r];
          out[BS*SSEL*5 + o] = (float)w->bd.lab[b][r];
          out[BS*SSEL*6 + o] = (float)r;
        }
        ++p;
      }
    }
    for (int slot = tid; slot < SSEL; slot += 1024){
      if ((uint32_t)slot >= totalK){
        int o = b*SSEL + slot;
        out[o*4 + 0] = 0.0f; out[o*4 + 1] = 0.0f;
        out[o*4 + 2] = 0.0f; out[o*4 + 3] = 0.0f;
        out[BS*SSEL*4 + o] = 0.0f;
        out[BS*SSEL*5 + o] = -1.0f;
        out[BS*SSEL*6 + o] = -1.0f;
      }
    }
  }
}

extern "C" void kernel_launch(void* const* d_in, const int* in_sizes, int n_in,
                              void* d_out, int out_size, void* d_ws, size_t ws_size,
                              hipStream_t stream){
  (void)in_sizes; (void)n_in; (void)out_size;
  if (ws_size < sizeof(WS)) return;   // ~5 MB scratch required
  const float4* logits = (const float4*)d_in[0];
  const float*  pboxes = (const float*)d_in[1];
  const float*  tsz    = (const float*)d_in[3];
  float* out = (float*)d_out;
  WS* w = (WS*)d_ws;

  (void)hipMemsetAsync(d_ws, 0, sizeof(WSHead), stream);
  k_hist1  <<<dim3(128, BS), 256, 0, stream>>>(logits, w);
  k_sel1   <<<BS, 1024, 0, stream>>>(w);
  k_hist2  <<<dim3(128, BS), 256, 0, stream>>>(logits, w);
  k_sel2   <<<BS, 1024, 0, stream>>>(w);
  k_compact<<<dim3(128, BS), 256, 0, stream>>>(logits, w);
  k_rankp  <<<dim3(CAP/IPB, CAP/SEGLEN, BS), 256, 0, stream>>>(w);
  k_tail   <<<BS, 1024, 0, stream>>>(w, pboxes, tsz, out);
}

// Round 10
// 250.297 us; speedup vs baseline: 2.2183x; 2.2183x over previous
//
#include <hip/hip_runtime.h>
#include <hip/hip_bf16.h>
#include <stdint.h>

// Match numpy/XLA elementwise rounding: no FMA contraction anywhere in ref math.
#pragma clang fp contract(off)

#define BS 4
#define NQ 900
#define NC 1203
#define NCAND (NQ*NC)      // 1082700
#define N4 (NCAND/4)       // 270675 (exact)
#define TOPK 10000
#define SSEL 300
#define CAP 16384
#define ECAP 65536
#define TARGET 10240       // top-k margin over 10000 for sigmoid tie-groups
#define SEGLEN 256         // rank: keys per LDS segment (fixed-trip, zero-padded)
#define IPT 16             // rank: i-keys per thread (ILP depth)
#define IPB (256*IPT)      // 4096 i-keys per block

struct WSHead {                       // zero-initialized via one memset
  uint32_t ghist1[BS][4096];
  uint32_t ghist2[BS][4096];
  uint32_t ccnt[BS][NC];
  uint32_t cfill[BS][NC];
  uint32_t rnk[BS][CAP];              // partial rank counts (zeroed)
  uint32_t compCnt[BS];
  uint32_t ecnt[BS];
  uint32_t gmaxOrd[BS];
  uint32_t gminNegOrd[BS];
  uint32_t B12v[BS];
  uint32_t cntAbove[BS];
  uint32_t Tkey[BS];
  uint32_t pad[64];
};
struct WSBody {                       // fully overwritten before any read
  uint64_t skey[BS][CAP];
  float    srtS[BS][TOPK];
  float    bx4[BS][TOPK][4];
  int32_t  lab[BS][TOPK];
  float    x1o[BS][TOPK];
  float    y1o[BS][TOPK];
  float    x2o[BS][TOPK];
  float    y2o[BS][TOPK];
  float    areaA[BS][TOPK];
  uint32_t entry[BS][TOPK];
  uint32_t cstart[BS][NC+1];
  uint32_t eI[BS][ECAP];
  uint32_t eJ[BS][ECAP];
};
struct WS { WSHead h; WSBody bd; };   // ~5.3 MB total

__device__ __forceinline__ uint32_t ordkey(float f){
  uint32_t u = __float_as_uint(f);
  return u ^ ((u & 0x80000000u) ? 0xFFFFFFFFu : 0x80000000u);
}
__device__ __forceinline__ float invord(uint32_t k){
  uint32_t u = (k & 0x80000000u) ? (k ^ 0x80000000u) : ~k;
  return __uint_as_float(u);
}

// XLA:CPU-style Cephes expf — verified bit-exact (absmax 0.0). DO NOT TOUCH.
__device__ __forceinline__ float ref_expf(float x){
  float xc = fminf(fmaxf(x, -87.3365478515625f), 88.3762626647949f);
  float fx = floorf(fmaf(xc, 1.44269504088896341f, 0.5f));
  float r  = fmaf(fx, -0.693359375f, xc);
  r = fmaf(fx, 2.12194440e-4f, r);
  float r2 = r*r;
  float y = fmaf(1.9875691500E-4f, r, 1.3981999507E-3f);
  y = fmaf(y, r, 8.3334519073E-3f);
  y = fmaf(y, r, 4.1665795894E-2f);
  y = fmaf(y, r, 1.6666665459E-1f);
  y = fmaf(y, r, 5.0000001201E-1f);
  y = fmaf(y, r2, r);
  y = y + 1.0f;
  float p2n = __uint_as_float((uint32_t)(((int)fx + 127) << 23));
  return y * p2n;
}
__device__ __forceinline__ float ref_sigmoid(float x){
  return 1.0f / (1.0f + ref_expf(-x));
}

// ---------------- pass 1: coarse 12-bit histogram of ordered logit keys ----
__global__ void k_hist1(const float4* __restrict__ L, WS* w){
  int b = blockIdx.y;
  __shared__ uint32_t h[4096];
  for (int i = threadIdx.x; i < 4096; i += blockDim.x) h[i] = 0;
  __syncthreads();
  const float4* Lb = L + (size_t)b * N4;
  for (int i = blockIdx.x*blockDim.x + threadIdx.x; i < N4; i += gridDim.x*blockDim.x){
    float4 v = Lb[i];
    atomicAdd(&h[ordkey(v.x)>>20], 1u);
    atomicAdd(&h[ordkey(v.y)>>20], 1u);
    atomicAdd(&h[ordkey(v.z)>>20], 1u);
    atomicAdd(&h[ordkey(v.w)>>20], 1u);
  }
  __syncthreads();
  for (int i = threadIdx.x; i < 4096; i += blockDim.x){
    uint32_t c = h[i];
    if (c) atomicAdd(&w->h.ghist1[b][i], c);   // no return value -> fire-and-forget
  }
}

// parallel suffix-scan selection: B12 = max bin with suffixInc(bin) >= TARGET
__global__ void __launch_bounds__(1024) k_sel1(WS* w){
  int b = blockIdx.x;
  int t = threadIdx.x;
  __shared__ uint32_t ts[1024];
  uint32_t v0 = w->h.ghist1[b][4*t+0];
  uint32_t v1 = w->h.ghist1[b][4*t+1];
  uint32_t v2 = w->h.ghist1[b][4*t+2];
  uint32_t v3 = w->h.ghist1[b][4*t+3];
  uint32_t mysum = v0+v1+v2+v3;
  ts[t] = mysum;
  __syncthreads();
  for (int off = 1; off < 1024; off <<= 1){       // inclusive SUFFIX scan
    uint32_t add = (t + off < 1024) ? ts[t + off] : 0;
    __syncthreads();
    ts[t] += add;
    __syncthreads();
  }
  uint32_t above = (t < 1023) ? ts[t+1] : 0;      // sum of bins >= 4(t+1)
  uint32_t si3 = v3 + above;
  uint32_t si2 = v2 + si3;
  uint32_t si1 = v1 + si2;
  uint32_t si0 = v0 + si1;
  if (si3 >= TARGET && above < TARGET){ w->h.B12v[b] = 4*t+3; w->h.cntAbove[b] = above; }
  if (si2 >= TARGET && si3   < TARGET){ w->h.B12v[b] = 4*t+2; w->h.cntAbove[b] = si3; }
  if (si1 >= TARGET && si2   < TARGET){ w->h.B12v[b] = 4*t+1; w->h.cntAbove[b] = si2; }
  if (si0 >= TARGET && si1   < TARGET){ w->h.B12v[b] = 4*t+0; w->h.cntAbove[b] = si1; }
}

// ---------------- pass 2: refine within boundary bucket (next 12 bits) -----
__global__ void k_hist2(const float4* __restrict__ L, WS* w){
  int b = blockIdx.y;
  uint32_t B = w->h.B12v[b];
  const float4* Lb = L + (size_t)b * N4;
  for (int i = blockIdx.x*blockDim.x + threadIdx.x; i < N4; i += gridDim.x*blockDim.x){
    float4 v = Lb[i];
    uint32_t k;
    k = ordkey(v.x); if ((k>>20) == B) atomicAdd(&w->h.ghist2[b][(k>>8)&0xFFFu], 1u);
    k = ordkey(v.y); if ((k>>20) == B) atomicAdd(&w->h.ghist2[b][(k>>8)&0xFFFu], 1u);
    k = ordkey(v.z); if ((k>>20) == B) atomicAdd(&w->h.ghist2[b][(k>>8)&0xFFFu], 1u);
    k = ordkey(v.w); if ((k>>20) == B) atomicAdd(&w->h.ghist2[b][(k>>8)&0xFFFu], 1u);
  }
}

__global__ void __launch_bounds__(1024) k_sel2(WS* w){
  int b = blockIdx.x;
  int t = threadIdx.x;
  uint32_t A = w->h.cntAbove[b];
  uint32_t B = w->h.B12v[b];
  __shared__ uint32_t ts[1024];
  uint32_t v0 = w->h.ghist2[b][4*t+0];
  uint32_t v1 = w->h.ghist2[b][4*t+1];
  uint32_t v2 = w->h.ghist2[b][4*t+2];
  uint32_t v3 = w->h.ghist2[b][4*t+3];
  uint32_t mysum = v0+v1+v2+v3;
  ts[t] = mysum;
  __syncthreads();
  for (int off = 1; off < 1024; off <<= 1){       // inclusive SUFFIX scan
    uint32_t add = (t + off < 1024) ? ts[t + off] : 0;
    __syncthreads();
    ts[t] += add;
    __syncthreads();
  }
  uint32_t above = (t < 1023) ? ts[t+1] : 0;
  uint32_t si3 = v3 + above;
  uint32_t si2 = v2 + si3;
  uint32_t si1 = v1 + si2;
  uint32_t si0 = v0 + si1;
  if (A + si3 >= TARGET && A + above < TARGET) w->h.Tkey[b] = (B<<20) | ((uint32_t)(4*t+3)<<8);
  if (A + si2 >= TARGET && A + si3   < TARGET) w->h.Tkey[b] = (B<<20) | ((uint32_t)(4*t+2)<<8);
  if (A + si1 >= TARGET && A + si2   < TARGET) w->h.Tkey[b] = (B<<20) | ((uint32_t)(4*t+1)<<8);
  if (A + si0 >= TARGET && A + si1   < TARGET) w->h.Tkey[b] = (B<<20) | ((uint32_t)(4*t+0)<<8);
}

// ---------------- pass 3: SINGLE-sweep compaction via LDS staging ----------
// Passing candidates collect in a 2048-entry LDS buffer (expected ~80/block);
// ONE global atomic per block reserves the output range; bulk copy follows.
// Correct spill path for the (practically impossible) overflow. Emission
// order is irrelevant downstream (rankp sorts by value).
__global__ void k_compact(const float4* __restrict__ L, WS* w){
  int b = blockIdx.y;
  uint32_t T = w->h.Tkey[b];
  const float4* Lb = L + (size_t)b * N4;
  __shared__ uint64_t buf[2048];
  __shared__ uint32_t lcnt, gbase;
  if (threadIdx.x == 0) lcnt = 0;
  __syncthreads();
  for (int i = blockIdx.x*blockDim.x + threadIdx.x; i < N4; i += gridDim.x*blockDim.x){
    float4 v = Lb[i];
    float c4[4] = {v.x, v.y, v.z, v.w};
    #pragma unroll
    for (int c = 0; c < 4; ++c){
      uint32_t k = ordkey(c4[c]);
      if (k >= T){
        float s = ref_sigmoid(c4[c]);
        uint32_t idx = (uint32_t)(i*4 + c);
        uint64_t key = ((uint64_t)__float_as_uint(s) << 32) | (uint32_t)(~idx);
        uint32_t p = atomicAdd(&lcnt, 1u);         // LDS atomic (fast)
        if (p < 2048u) buf[p] = key;
        else {                                     // spill (never in practice)
          uint32_t g = atomicAdd(&w->h.compCnt[b], 1u);
          if (g < CAP) w->bd.skey[b][g] = key;
        }
      }
    }
  }
  __syncthreads();
  uint32_t n = lcnt; if (n > 2048u) n = 2048u;
  if (threadIdx.x == 0) gbase = (n > 0) ? atomicAdd(&w->h.compCnt[b], n) : 0;
  __syncthreads();
  for (uint32_t u = threadIdx.x; u < n; u += blockDim.x){
    uint32_t g = gbase + u;
    if (g < CAP) w->bd.skey[b][g] = buf[u];
  }
}

// O(C^2) rank via 2-D (i-chunk x key-segment) partial counts.
// IPT=16 i-keys/thread: each LDS broadcast read feeds 16 compares (2x round-8
// arithmetic per load). Fixed-trip zero-padded tile (pad key 0 < every real
// key since sigmoid bits > 0 -> counts exact).
__global__ void __launch_bounds__(256) k_rankp(WS* w){
  int b = blockIdx.z;
  uint32_t C = w->h.compCnt[b]; if (C > CAP) C = CAP;
  uint32_t i0 = blockIdx.x * IPB;
  uint32_t s0 = blockIdx.y * SEGLEN;
  if (i0 >= C || s0 >= C) return;            // uniform whole-block exit
  const uint64_t* __restrict__ K = w->bd.skey[b];
  __shared__ uint64_t tile[SEGLEN];
  tile[threadIdx.x] = (s0 + threadIdx.x < C) ? K[s0 + threadIdx.x] : 0ull;
  uint64_t mine[IPT];
  uint32_t cnt[IPT];
  #pragma unroll
  for (int k = 0; k < IPT; ++k){
    uint32_t i = i0 + k*256u + threadIdx.x;
    mine[k] = (i < C) ? K[i] : ~0ull;        // sentinel lanes never flush
    cnt[k] = 0;
  }
  __syncthreads();
  for (uint32_t u = 0; u < SEGLEN; u += 8){
    uint64_t t0 = tile[u  ], t1 = tile[u+1], t2 = tile[u+2], t3 = tile[u+3];
    uint64_t t4 = tile[u+4], t5 = tile[u+5], t6 = tile[u+6], t7 = tile[u+7];
    #pragma unroll
    for (int k = 0; k < IPT; ++k)
      cnt[k] += (uint32_t)(t0 > mine[k]) + (uint32_t)(t1 > mine[k])
              + (uint32_t)(t2 > mine[k]) + (uint32_t)(t3 > mine[k])
              + (uint32_t)(t4 > mine[k]) + (uint32_t)(t5 > mine[k])
              + (uint32_t)(t6 > mine[k]) + (uint32_t)(t7 > mine[k]);
  }
  #pragma unroll
  for (int k = 0; k < IPT; ++k){
    uint32_t i = i0 + k*256u + threadIdx.x;
    if (i < C && cnt[k]) atomicAdd(&w->h.rnk[b][i], cnt[k]);
  }
}

// place+gather fused, per-candidate: r = rnk[i] (a permutation of 0..C-1).
// Writes box (cxcywh->xyxy, scaled), label, score at rank slot; counts labels;
// reduces per-batch max/min coordinate.
__global__ void k_pg(WS* w, const float* __restrict__ pboxes,
                     const float* __restrict__ tsz){
  int b = blockIdx.y;
  uint32_t C = w->h.compCnt[b]; if (C > CAP) C = CAP;
  uint32_t i = blockIdx.x*blockDim.x + threadIdx.x;
  uint32_t mo = 0, mno = 0;
  if (i < C){
    uint32_t r = w->h.rnk[b][i];
    if (r < TOPK){
      uint64_t key = w->bd.skey[b][i];
      uint32_t idx = ~(uint32_t)key;
      uint32_t q = idx / NC;
      uint32_t c = idx - q*NC;
      const float* pb = pboxes + ((size_t)b*NQ + q)*4;
      float cx = pb[0], cy = pb[1], bw = pb[2], bh = pb[3];
      float hw = 0.5f*bw, hh = 0.5f*bh;
      float x1 = cx - hw, y1 = cy - hh, x2 = cx + hw, y2 = cy + hh;
      float ihh = tsz[b*2 + 0], iww = tsz[b*2 + 1];
      float b0 = x1*iww, b1 = y1*ihh, b2 = x2*iww, b3 = y2*ihh;
      w->bd.bx4[b][r][0] = b0; w->bd.bx4[b][r][1] = b1;
      w->bd.bx4[b][r][2] = b2; w->bd.bx4[b][r][3] = b3;
      w->bd.lab[b][r] = (int)c;
      w->bd.srtS[b][r] = __uint_as_float((uint32_t)(key >> 32));
      atomicAdd(&w->h.ccnt[b][c], 1u);       // fire-and-forget
      float mx = fmaxf(fmaxf(b0,b1), fmaxf(b2,b3));
      float mn = fminf(fminf(b0,b1), fminf(b2,b3));
      mo = ordkey(mx); mno = ~ordkey(mn);
    }
  }
  #pragma unroll
  for (int off = 32; off; off >>= 1){
    uint32_t a = (uint32_t)__shfl_xor((int)mo, off, 64);
    uint32_t c2 = (uint32_t)__shfl_xor((int)mno, off, 64);
    mo = mo > a ? mo : a;
    mno = mno > c2 ? mno : c2;
  }
  if ((threadIdx.x & 63u) == 0){
    atomicMax(&w->h.gmaxOrd[b], mo);
    atomicMax(&w->h.gminNegOrd[b], mno);
  }
}

// parallel exclusive prefix scan over 1203 class counts
__global__ void __launch_bounds__(1024) k_cstart(WS* w){
  int b = blockIdx.x;
  int t = threadIdx.x;
  __shared__ uint32_t ts[1024];
  uint32_t v0 = (2*t   < NC) ? w->h.ccnt[b][2*t]   : 0;
  uint32_t v1 = (2*t+1 < NC) ? w->h.ccnt[b][2*t+1] : 0;
  uint32_t mysum = v0 + v1;
  ts[t] = mysum;
  __syncthreads();
  for (int off = 1; off < 1024; off <<= 1){       // inclusive PREFIX scan
    uint32_t add = (t >= off) ? ts[t - off] : 0;
    __syncthreads();
    ts[t] += add;
    __syncthreads();
  }
  uint32_t base = ts[t] - mysum;                  // exclusive
  if (2*t   <= NC) w->bd.cstart[b][2*t]   = base;
  if (2*t+1 <= NC) w->bd.cstart[b][2*t+1] = base + v0;
}

// offs+scatter fused: offset boxes by label*(max_c+1) exactly like the
// reference, store offset coords/areas, scatter rank into its class bucket.
__global__ void k_os(WS* w){
  int b = blockIdx.y;
  int r = blockIdx.x*blockDim.x + threadIdx.x;
  if (r >= TOPK) return;
  float maxc = invord(w->h.gmaxOrd[b]);
  float M = maxc + 1.0f;
  int c = w->bd.lab[b][r];
  float off = (float)c * M;
  float x1 = w->bd.bx4[b][r][0] + off;
  float y1 = w->bd.bx4[b][r][1] + off;
  float x2 = w->bd.bx4[b][r][2] + off;
  float y2 = w->bd.bx4[b][r][3] + off;
  float area = (x2 - x1) * (y2 - y1);
  w->bd.x1o[b][r] = x1; w->bd.y1o[b][r] = y1;
  w->bd.x2o[b][r] = x2; w->bd.y2o[b][r] = y2;
  w->bd.areaA[b][r] = area;
  uint32_t pos = w->bd.cstart[b][c] + atomicAdd(&w->h.cfill[b][c], 1u);
  w->bd.entry[b][pos] = (uint32_t)r;
}

// conflict edges: rank i < j, iou(offset boxes) > 0.7; class window provably covers
__global__ void k_edges(WS* w){
  int b = blockIdx.y;
  int j = blockIdx.x*blockDim.x + threadIdx.x;
  if (j >= TOPK) return;
  float maxc = invord(w->h.gmaxOrd[b]);
  float minc = invord(~w->h.gminNegOrd[b]);
  float M = maxc + 1.0f;
  float span = maxc - minc;
  int D;
  if (M > 0.0f){ D = (int)floorf(span / M); if (D < 0) D = 0; if (D > NC-1) D = NC-1; }
  else D = NC-1;
  int cj = w->bd.lab[b][j];
  float X1 = w->bd.x1o[b][j], Y1 = w->bd.y1o[b][j];
  float X2 = w->bd.x2o[b][j], Y2 = w->bd.y2o[b][j];
  float A  = w->bd.areaA[b][j];
  int c0 = cj - D; if (c0 < 0) c0 = 0;
  int c1 = cj + D; if (c1 > NC-1) c1 = NC-1;
  for (int cc = c0; cc <= c1; ++cc){
    uint32_t t0 = w->bd.cstart[b][cc], t1 = w->bd.cstart[b][cc+1];
    for (uint32_t t = t0; t < t1; ++t){
      uint32_t i = w->bd.entry[b][t];
      if (i >= (uint32_t)j) continue;
      float iw = fminf(w->bd.x2o[b][i], X2) - fmaxf(w->bd.x1o[b][i], X1);
      iw = fmaxf(iw, 0.0f);
      float ih = fminf(w->bd.y2o[b][i], Y2) - fmaxf(w->bd.y1o[b][i], Y1);
      ih = fmaxf(ih, 0.0f);
      float inter = iw * ih;
      float den = (w->bd.areaA[b][i] + A) - inter;
      float iou = inter / den;            // NaN (0/0) compares false, like numpy
      if (iou > 0.7f){
        uint32_t n = atomicAdd(&w->h.ecnt[b], 1u);
        if (n < ECAP){ w->bd.eI[b][n] = i; w->bd.eJ[b][n] = (uint32_t)j; }
      }
    }
  }
}

// fixpoint NMS (race-fixed) + in-LDS stable compaction of kept ranks -> output
__global__ void __launch_bounds__(1024) k_nmsout(WS* w, float* __restrict__ out){
  int b = blockIdx.x;
  int tid = threadIdx.x;
  __shared__ uint8_t keep[TOPK];
  __shared__ uint8_t supp[TOPK];
  __shared__ uint32_t ps[1024];
  __shared__ int changed;
  for (int r = tid; r < TOPK; r += blockDim.x) keep[r] = 1;
  uint32_t E = w->h.ecnt[b]; if (E > ECAP) E = ECAP;
  const uint32_t* ei = w->bd.eI[b];
  const uint32_t* ej = w->bd.eJ[b];
  for (int round = 0; round < 128; ++round){
    for (int r = tid; r < TOPK; r += blockDim.x) supp[r] = 0;
    if (tid == 0) changed = 0;
    __syncthreads();
    for (uint32_t e = tid; e < E; e += blockDim.x)
      if (keep[ei[e]]) supp[ej[e]] = 1;
    __syncthreads();
    for (int r = tid; r < TOPK; r += blockDim.x){
      uint8_t nk = (uint8_t)(1 - supp[r]);
      if (nk != keep[r]){ keep[r] = nk; changed = 1; }
    }
    __syncthreads();
    int ch = changed;          // uniform snapshot
    __syncthreads();           // all reads complete before next round's write
    if (!ch) break;            // uniform branch
  }
  // ---- compaction phase (keep[] stable behind the barriers above) ----
  int r0 = tid * 10;
  uint32_t cnt = 0;
  for (int u = 0; u < 10; ++u){ int r = r0 + u; if (r < TOPK) cnt += keep[r]; }
  ps[tid] = cnt;
  __syncthreads();
  for (int off = 1; off < 1024; off <<= 1){
    uint32_t v = 0;
    if (tid >= off) v = ps[tid - off];
    __syncthreads();
    if (tid >= off) ps[tid] += v;
    __syncthreads();
  }
  uint32_t totalK = ps[1023];
  uint32_t p = ps[tid] - cnt;
  for (int u = 0; u < 10; ++u){
    int r = r0 + u; if (r >= TOPK) break;
    if (keep[r]){
      if (p < SSEL){
        int o = b*SSEL + (int)p;
        out[o*4 + 0] = w->bd.bx4[b][r][0];
        out[o*4 + 1] = w->bd.bx4[b][r][1];
        out[o*4 + 2] = w->bd.bx4[b][r][2];
        out[o*4 + 3] = w->bd.bx4[b][r][3];
        out[BS*SSEL*4 + o] = w->bd.srtS[b][r];
        out[BS*SSEL*5 + o] = (float)w->bd.lab[b][r];
        out[BS*SSEL*6 + o] = (float)r;
      }
      ++p;
    }
  }
  for (int slot = tid; slot < SSEL; slot += 1024){
    if ((uint32_t)slot >= totalK){
      int o = b*SSEL + slot;
      out[o*4 + 0] = 0.0f; out[o*4 + 1] = 0.0f;
      out[o*4 + 2] = 0.0f; out[o*4 + 3] = 0.0f;
      out[BS*SSEL*4 + o] = 0.0f;
      out[BS*SSEL*5 + o] = -1.0f;
      out[BS*SSEL*6 + o] = -1.0f;
    }
  }
}

extern "C" void kernel_launch(void* const* d_in, const int* in_sizes, int n_in,
                              void* d_out, int out_size, void* d_ws, size_t ws_size,
                              hipStream_t stream){
  (void)in_sizes; (void)n_in; (void)out_size;
  if (ws_size < sizeof(WS)) return;   // ~5.3 MB scratch required
  const float4* logits = (const float4*)d_in[0];
  const float*  pboxes = (const float*)d_in[1];
  const float*  tsz    = (const float*)d_in[3];
  float* out = (float*)d_out;
  WS* w = (WS*)d_ws;

  (void)hipMemsetAsync(d_ws, 0, sizeof(WSHead), stream);
  k_hist1  <<<dim3(128, BS), 256, 0, stream>>>(logits, w);
  k_sel1   <<<BS, 1024, 0, stream>>>(w);
  k_hist2  <<<dim3(128, BS), 256, 0, stream>>>(logits, w);
  k_sel2   <<<BS, 1024, 0, stream>>>(w);
  k_compact<<<dim3(128, BS), 256, 0, stream>>>(logits, w);
  k_rankp  <<<dim3(CAP/IPB, CAP/SEGLEN, BS), 256, 0, stream>>>(w);
  k_pg     <<<dim3(CAP/256, BS), 256, 0, stream>>>(w, pboxes, tsz);
  k_cstart <<<BS, 1024, 0, stream>>>(w);
  k_os     <<<dim3(40, BS), 256, 0, stream>>>(w);
  k_edges  <<<dim3(40, BS), 256, 0, stream>>>(w);
  k_nmsout <<<BS, 1024, 0, stream>>>(w, out);
}

// Round 11
// 247.767 us; speedup vs baseline: 2.2410x; 1.0102x over previous
//
#include <hip/hip_runtime.h>
#include <hip/hip_bf16.h>
#include <stdint.h>

// Match numpy/XLA elementwise rounding: no FMA contraction anywhere in ref math.
#pragma clang fp contract(off)

#define BS 4
#define NQ 900
#define NC 1203
#define NCAND (NQ*NC)      // 1082700
#define N4 (NCAND/4)       // 270675 (exact)
#define TOPK 10000
#define SSEL 300
#define CAP 16384
#define ECAP 65536
#define TARGET 10240       // top-k margin over 10000 for sigmoid tie-groups
#define SEGLEN 256         // rank: keys per LDS segment (fixed-trip, zero-padded)
#define IPT 8              // rank: i-keys per thread
#define IPB (256*IPT)      // 2048 i-keys per block

struct WSHead {                       // zero-initialized via one memset
  uint32_t ghist1[BS][4096];
  uint32_t ghist2[BS][4096];
  uint32_t ccnt[BS][NC];
  uint32_t cfill[BS][NC];
  uint32_t rnk[BS][CAP];              // partial rank counts (zeroed)
  uint32_t compCnt[BS];
  uint32_t ecnt[BS];
  uint32_t gmaxOrd[BS];
  uint32_t gminNegOrd[BS];
  uint32_t B12v[BS];
  uint32_t cntAbove[BS];
  uint32_t Tkey[BS];
  uint32_t pad[64];
};
struct WSBody {                       // fully overwritten before any read
  uint64_t skey[BS][CAP];
  float    srtS[BS][TOPK];
  float    bx4[BS][TOPK][4];
  int32_t  lab[BS][TOPK];
  float    x1o[BS][TOPK];
  float    y1o[BS][TOPK];
  float    x2o[BS][TOPK];
  float    y2o[BS][TOPK];
  float    areaA[BS][TOPK];
  uint32_t entry[BS][TOPK];
  uint32_t cstart[BS][NC+1];
  uint32_t eI[BS][ECAP];
  uint32_t eJ[BS][ECAP];
};
struct WS { WSHead h; WSBody bd; };   // ~5.3 MB total

__device__ __forceinline__ uint32_t ordkey(float f){
  uint32_t u = __float_as_uint(f);
  return u ^ ((u & 0x80000000u) ? 0xFFFFFFFFu : 0x80000000u);
}
__device__ __forceinline__ float invord(uint32_t k){
  uint32_t u = (k & 0x80000000u) ? (k ^ 0x80000000u) : ~k;
  return __uint_as_float(u);
}

// XLA:CPU-style Cephes expf — verified bit-exact (absmax 0.0). DO NOT TOUCH.
__device__ __forceinline__ float ref_expf(float x){
  float xc = fminf(fmaxf(x, -87.3365478515625f), 88.3762626647949f);
  float fx = floorf(fmaf(xc, 1.44269504088896341f, 0.5f));
  float r  = fmaf(fx, -0.693359375f, xc);
  r = fmaf(fx, 2.12194440e-4f, r);
  float r2 = r*r;
  float y = fmaf(1.9875691500E-4f, r, 1.3981999507E-3f);
  y = fmaf(y, r, 8.3334519073E-3f);
  y = fmaf(y, r, 4.1665795894E-2f);
  y = fmaf(y, r, 1.6666665459E-1f);
  y = fmaf(y, r, 5.0000001201E-1f);
  y = fmaf(y, r2, r);
  y = y + 1.0f;
  float p2n = __uint_as_float((uint32_t)(((int)fx + 127) << 23));
  return y * p2n;
}
__device__ __forceinline__ float ref_sigmoid(float x){
  return 1.0f / (1.0f + ref_expf(-x));
}

// ---------------- pass 1: coarse 12-bit histogram of ordered logit keys ----
__global__ void k_hist1(const float4* __restrict__ L, WS* w){
  int b = blockIdx.y;
  __shared__ uint32_t h[4096];
  for (int i = threadIdx.x; i < 4096; i += blockDim.x) h[i] = 0;
  __syncthreads();
  const float4* Lb = L + (size_t)b * N4;
  for (int i = blockIdx.x*blockDim.x + threadIdx.x; i < N4; i += gridDim.x*blockDim.x){
    float4 v = Lb[i];
    atomicAdd(&h[ordkey(v.x)>>20], 1u);
    atomicAdd(&h[ordkey(v.y)>>20], 1u);
    atomicAdd(&h[ordkey(v.z)>>20], 1u);
    atomicAdd(&h[ordkey(v.w)>>20], 1u);
  }
  __syncthreads();
  for (int i = threadIdx.x; i < 4096; i += blockDim.x){
    uint32_t c = h[i];
    if (c) atomicAdd(&w->h.ghist1[b][i], c);   // no return value -> fire-and-forget
  }
}

// parallel suffix-scan selection: B12 = max bin with suffixInc(bin) >= TARGET
__global__ void __launch_bounds__(1024) k_sel1(WS* w){
  int b = blockIdx.x;
  int t = threadIdx.x;
  __shared__ uint32_t ts[1024];
  uint32_t v0 = w->h.ghist1[b][4*t+0];
  uint32_t v1 = w->h.ghist1[b][4*t+1];
  uint32_t v2 = w->h.ghist1[b][4*t+2];
  uint32_t v3 = w->h.ghist1[b][4*t+3];
  uint32_t mysum = v0+v1+v2+v3;
  ts[t] = mysum;
  __syncthreads();
  for (int off = 1; off < 1024; off <<= 1){       // inclusive SUFFIX scan
    uint32_t add = (t + off < 1024) ? ts[t + off] : 0;
    __syncthreads();
    ts[t] += add;
    __syncthreads();
  }
  uint32_t above = (t < 1023) ? ts[t+1] : 0;      // sum of bins >= 4(t+1)
  uint32_t si3 = v3 + above;
  uint32_t si2 = v2 + si3;
  uint32_t si1 = v1 + si2;
  uint32_t si0 = v0 + si1;
  if (si3 >= TARGET && above < TARGET){ w->h.B12v[b] = 4*t+3; w->h.cntAbove[b] = above; }
  if (si2 >= TARGET && si3   < TARGET){ w->h.B12v[b] = 4*t+2; w->h.cntAbove[b] = si3; }
  if (si1 >= TARGET && si2   < TARGET){ w->h.B12v[b] = 4*t+1; w->h.cntAbove[b] = si2; }
  if (si0 >= TARGET && si1   < TARGET){ w->h.B12v[b] = 4*t+0; w->h.cntAbove[b] = si1; }
}

// ---------------- pass 2: refine within boundary bucket (next 12 bits) -----
__global__ void k_hist2(const float4* __restrict__ L, WS* w){
  int b = blockIdx.y;
  uint32_t B = w->h.B12v[b];
  const float4* Lb = L + (size_t)b * N4;
  for (int i = blockIdx.x*blockDim.x + threadIdx.x; i < N4; i += gridDim.x*blockDim.x){
    float4 v = Lb[i];
    uint32_t k;
    k = ordkey(v.x); if ((k>>20) == B) atomicAdd(&w->h.ghist2[b][(k>>8)&0xFFFu], 1u);
    k = ordkey(v.y); if ((k>>20) == B) atomicAdd(&w->h.ghist2[b][(k>>8)&0xFFFu], 1u);
    k = ordkey(v.z); if ((k>>20) == B) atomicAdd(&w->h.ghist2[b][(k>>8)&0xFFFu], 1u);
    k = ordkey(v.w); if ((k>>20) == B) atomicAdd(&w->h.ghist2[b][(k>>8)&0xFFFu], 1u);
  }
}

__global__ void __launch_bounds__(1024) k_sel2(WS* w){
  int b = blockIdx.x;
  int t = threadIdx.x;
  uint32_t A = w->h.cntAbove[b];
  uint32_t B = w->h.B12v[b];
  __shared__ uint32_t ts[1024];
  uint32_t v0 = w->h.ghist2[b][4*t+0];
  uint32_t v1 = w->h.ghist2[b][4*t+1];
  uint32_t v2 = w->h.ghist2[b][4*t+2];
  uint32_t v3 = w->h.ghist2[b][4*t+3];
  uint32_t mysum = v0+v1+v2+v3;
  ts[t] = mysum;
  __syncthreads();
  for (int off = 1; off < 1024; off <<= 1){       // inclusive SUFFIX scan
    uint32_t add = (t + off < 1024) ? ts[t + off] : 0;
    __syncthreads();
    ts[t] += add;
    __syncthreads();
  }
  uint32_t above = (t < 1023) ? ts[t+1] : 0;
  uint32_t si3 = v3 + above;
  uint32_t si2 = v2 + si3;
  uint32_t si1 = v1 + si2;
  uint32_t si0 = v0 + si1;
  if (A + si3 >= TARGET && A + above < TARGET) w->h.Tkey[b] = (B<<20) | ((uint32_t)(4*t+3)<<8);
  if (A + si2 >= TARGET && A + si3   < TARGET) w->h.Tkey[b] = (B<<20) | ((uint32_t)(4*t+2)<<8);
  if (A + si1 >= TARGET && A + si2   < TARGET) w->h.Tkey[b] = (B<<20) | ((uint32_t)(4*t+1)<<8);
  if (A + si0 >= TARGET && A + si1   < TARGET) w->h.Tkey[b] = (B<<20) | ((uint32_t)(4*t+0)<<8);
}

// ---------------- pass 3: SINGLE-sweep compaction via LDS staging ----------
// Passing candidates collect in a 2048-entry LDS buffer (expected ~80/block);
// ONE global atomic per block reserves the output range; bulk copy follows.
// Correct spill path for the (practically impossible) overflow. Emission
// order is irrelevant downstream (rankp sorts by value).
__global__ void k_compact(const float4* __restrict__ L, WS* w){
  int b = blockIdx.y;
  uint32_t T = w->h.Tkey[b];
  const float4* Lb = L + (size_t)b * N4;
  __shared__ uint64_t buf[2048];
  __shared__ uint32_t lcnt, gbase;
  if (threadIdx.x == 0) lcnt = 0;
  __syncthreads();
  for (int i = blockIdx.x*blockDim.x + threadIdx.x; i < N4; i += gridDim.x*blockDim.x){
    float4 v = Lb[i];
    float c4[4] = {v.x, v.y, v.z, v.w};
    #pragma unroll
    for (int c = 0; c < 4; ++c){
      uint32_t k = ordkey(c4[c]);
      if (k >= T){
        float s = ref_sigmoid(c4[c]);
        uint32_t idx = (uint32_t)(i*4 + c);
        uint64_t key = ((uint64_t)__float_as_uint(s) << 32) | (uint32_t)(~idx);
        uint32_t p = atomicAdd(&lcnt, 1u);         // LDS atomic (fast)
        if (p < 2048u) buf[p] = key;
        else {                                     // spill (never in practice)
          uint32_t g = atomicAdd(&w->h.compCnt[b], 1u);
          if (g < CAP) w->bd.skey[b][g] = key;
        }
      }
    }
  }
  __syncthreads();
  uint32_t n = lcnt; if (n > 2048u) n = 2048u;
  if (threadIdx.x == 0) gbase = (n > 0) ? atomicAdd(&w->h.compCnt[b], n) : 0;
  __syncthreads();
  for (uint32_t u = threadIdx.x; u < n; u += blockDim.x){
    uint32_t g = gbase + u;
    if (g < CAP) w->bd.skey[b][g] = buf[u];
  }
}

// O(C^2) rank via 2-D (i-chunk x key-segment) partial counts.
// KEY TRICK: keys (sigmoid_bits<<32 | ~idx) have bit63==0 and exponent field
// <= 1016, so every key reinterprets as a positive non-NaN double; for
// positive IEEE doubles bit order == numeric order, so one v_cmp_gt_f64
// replaces the ~4-inst u64 carry-chain compare. Pad 0 -> 0.0 < every key;
// sentinel ~0ull -> negative NaN -> all compares false (and i<C guards flush).
__global__ void __launch_bounds__(256) k_rankp(WS* w){
  int b = blockIdx.z;
  uint32_t C = w->h.compCnt[b]; if (C > CAP) C = CAP;
  uint32_t i0 = blockIdx.x * IPB;
  uint32_t s0 = blockIdx.y * SEGLEN;
  if (i0 >= C || s0 >= C) return;            // uniform whole-block exit
  const uint64_t* __restrict__ K = w->bd.skey[b];
  __shared__ uint64_t tile[SEGLEN];
  tile[threadIdx.x] = (s0 + threadIdx.x < C) ? K[s0 + threadIdx.x] : 0ull;
  double mine[IPT];
  uint32_t cnt[IPT];
  #pragma unroll
  for (int k = 0; k < IPT; ++k){
    uint32_t i = i0 + k*256u + threadIdx.x;
    mine[k] = __longlong_as_double((long long)((i < C) ? K[i] : ~0ull));
    cnt[k] = 0;
  }
  __syncthreads();
  for (uint32_t u = 0; u < SEGLEN; u += 8){
    double t0 = __longlong_as_double((long long)tile[u  ]);
    double t1 = __longlong_as_double((long long)tile[u+1]);
    double t2 = __longlong_as_double((long long)tile[u+2]);
    double t3 = __longlong_as_double((long long)tile[u+3]);
    double t4 = __longlong_as_double((long long)tile[u+4]);
    double t5 = __longlong_as_double((long long)tile[u+5]);
    double t6 = __longlong_as_double((long long)tile[u+6]);
    double t7 = __longlong_as_double((long long)tile[u+7]);
    #pragma unroll
    for (int k = 0; k < IPT; ++k)
      cnt[k] += (uint32_t)(t0 > mine[k]) + (uint32_t)(t1 > mine[k])
              + (uint32_t)(t2 > mine[k]) + (uint32_t)(t3 > mine[k])
              + (uint32_t)(t4 > mine[k]) + (uint32_t)(t5 > mine[k])
              + (uint32_t)(t6 > mine[k]) + (uint32_t)(t7 > mine[k]);
  }
  #pragma unroll
  for (int k = 0; k < IPT; ++k){
    uint32_t i = i0 + k*256u + threadIdx.x;
    if (i < C && cnt[k]) atomicAdd(&w->h.rnk[b][i], cnt[k]);
  }
}

// place+gather fused, per-candidate: r = rnk[i] (a permutation of 0..C-1).
// Writes box (cxcywh->xyxy, scaled), label, score at rank slot; counts labels;
// reduces per-batch max/min coordinate.
__global__ void k_pg(WS* w, const float* __restrict__ pboxes,
                     const float* __restrict__ tsz){
  int b = blockIdx.y;
  uint32_t C = w->h.compCnt[b]; if (C > CAP) C = CAP;
  uint32_t i = blockIdx.x*blockDim.x + threadIdx.x;
  uint32_t mo = 0, mno = 0;
  if (i < C){
    uint32_t r = w->h.rnk[b][i];
    if (r < TOPK){
      uint64_t key = w->bd.skey[b][i];
      uint32_t idx = ~(uint32_t)key;
      uint32_t q = idx / NC;
      uint32_t c = idx - q*NC;
      const float* pb = pboxes + ((size_t)b*NQ + q)*4;
      float cx = pb[0], cy = pb[1], bw = pb[2], bh = pb[3];
      float hw = 0.5f*bw, hh = 0.5f*bh;
      float x1 = cx - hw, y1 = cy - hh, x2 = cx + hw, y2 = cy + hh;
      float ihh = tsz[b*2 + 0], iww = tsz[b*2 + 1];
      float b0 = x1*iww, b1 = y1*ihh, b2 = x2*iww, b3 = y2*ihh;
      w->bd.bx4[b][r][0] = b0; w->bd.bx4[b][r][1] = b1;
      w->bd.bx4[b][r][2] = b2; w->bd.bx4[b][r][3] = b3;
      w->bd.lab[b][r] = (int)c;
      w->bd.srtS[b][r] = __uint_as_float((uint32_t)(key >> 32));
      atomicAdd(&w->h.ccnt[b][c], 1u);       // fire-and-forget
      float mx = fmaxf(fmaxf(b0,b1), fmaxf(b2,b3));
      float mn = fminf(fminf(b0,b1), fminf(b2,b3));
      mo = ordkey(mx); mno = ~ordkey(mn);
    }
  }
  #pragma unroll
  for (int off = 32; off; off >>= 1){
    uint32_t a = (uint32_t)__shfl_xor((int)mo, off, 64);
    uint32_t c2 = (uint32_t)__shfl_xor((int)mno, off, 64);
    mo = mo > a ? mo : a;
    mno = mno > c2 ? mno : c2;
  }
  if ((threadIdx.x & 63u) == 0){
    atomicMax(&w->h.gmaxOrd[b], mo);
    atomicMax(&w->h.gminNegOrd[b], mno);
  }
}

// parallel exclusive prefix scan over 1203 class counts
__global__ void __launch_bounds__(1024) k_cstart(WS* w){
  int b = blockIdx.x;
  int t = threadIdx.x;
  __shared__ uint32_t ts[1024];
  uint32_t v0 = (2*t   < NC) ? w->h.ccnt[b][2*t]   : 0;
  uint32_t v1 = (2*t+1 < NC) ? w->h.ccnt[b][2*t+1] : 0;
  uint32_t mysum = v0 + v1;
  ts[t] = mysum;
  __syncthreads();
  for (int off = 1; off < 1024; off <<= 1){       // inclusive PREFIX scan
    uint32_t add = (t >= off) ? ts[t - off] : 0;
    __syncthreads();
    ts[t] += add;
    __syncthreads();
  }
  uint32_t base = ts[t] - mysum;                  // exclusive
  if (2*t   <= NC) w->bd.cstart[b][2*t]   = base;
  if (2*t+1 <= NC) w->bd.cstart[b][2*t+1] = base + v0;
}

// offs+scatter fused: offset boxes by label*(max_c+1) exactly like the
// reference, store offset coords/areas, scatter rank into its class bucket.
__global__ void k_os(WS* w){
  int b = blockIdx.y;
  int r = blockIdx.x*blockDim.x + threadIdx.x;
  if (r >= TOPK) return;
  float maxc = invord(w->h.gmaxOrd[b]);
  float M = maxc + 1.0f;
  int c = w->bd.lab[b][r];
  float off = (float)c * M;
  float x1 = w->bd.bx4[b][r][0] + off;
  float y1 = w->bd.bx4[b][r][1] + off;
  float x2 = w->bd.bx4[b][r][2] + off;
  float y2 = w->bd.bx4[b][r][3] + off;
  float area = (x2 - x1) * (y2 - y1);
  w->bd.x1o[b][r] = x1; w->bd.y1o[b][r] = y1;
  w->bd.x2o[b][r] = x2; w->bd.y2o[b][r] = y2;
  w->bd.areaA[b][r] = area;
  uint32_t pos = w->bd.cstart[b][c] + atomicAdd(&w->h.cfill[b][c], 1u);
  w->bd.entry[b][pos] = (uint32_t)r;
}

// conflict edges: rank i < j, iou(offset boxes) > 0.7; class window provably covers
__global__ void k_edges(WS* w){
  int b = blockIdx.y;
  int j = blockIdx.x*blockDim.x + threadIdx.x;
  if (j >= TOPK) return;
  float maxc = invord(w->h.gmaxOrd[b]);
  float minc = invord(~w->h.gminNegOrd[b]);
  float M = maxc + 1.0f;
  float span = maxc - minc;
  int D;
  if (M > 0.0f){ D = (int)floorf(span / M); if (D < 0) D = 0; if (D > NC-1) D = NC-1; }
  else D = NC-1;
  int cj = w->bd.lab[b][j];
  float X1 = w->bd.x1o[b][j], Y1 = w->bd.y1o[b][j];
  float X2 = w->bd.x2o[b][j], Y2 = w->bd.y2o[b][j];
  float A  = w->bd.areaA[b][j];
  int c0 = cj - D; if (c0 < 0) c0 = 0;
  int c1 = cj + D; if (c1 > NC-1) c1 = NC-1;
  for (int cc = c0; cc <= c1; ++cc){
    uint32_t t0 = w->bd.cstart[b][cc], t1 = w->bd.cstart[b][cc+1];
    for (uint32_t t = t0; t < t1; ++t){
      uint32_t i = w->bd.entry[b][t];
      if (i >= (uint32_t)j) continue;
      float iw = fminf(w->bd.x2o[b][i], X2) - fmaxf(w->bd.x1o[b][i], X1);
      iw = fmaxf(iw, 0.0f);
      float ih = fminf(w->bd.y2o[b][i], Y2) - fmaxf(w->bd.y1o[b][i], Y1);
      ih = fmaxf(ih, 0.0f);
      float inter = iw * ih;
      float den = (w->bd.areaA[b][i] + A) - inter;
      float iou = inter / den;            // NaN (0/0) compares false, like numpy
      if (iou > 0.7f){
        uint32_t n = atomicAdd(&w->h.ecnt[b], 1u);
        if (n < ECAP){ w->bd.eI[b][n] = i; w->bd.eJ[b][n] = (uint32_t)j; }
      }
    }
  }
}

// fixpoint NMS (race-fixed) + in-LDS stable compaction of kept ranks -> output
__global__ void __launch_bounds__(1024) k_nmsout(WS* w, float* __restrict__ out){
  int b = blockIdx.x;
  int tid = threadIdx.x;
  __shared__ uint8_t keep[TOPK];
  __shared__ uint8_t supp[TOPK];
  __shared__ uint32_t ps[1024];
  __shared__ int changed;
  for (int r = tid; r < TOPK; r += blockDim.x) keep[r] = 1;
  uint32_t E = w->h.ecnt[b]; if (E > ECAP) E = ECAP;
  const uint32_t* ei = w->bd.eI[b];
  const uint32_t* ej = w->bd.eJ[b];
  for (int round = 0; round < 128; ++round){
    for (int r = tid; r < TOPK; r += blockDim.x) supp[r] = 0;
    if (tid == 0) changed = 0;
    __syncthreads();
    for (uint32_t e = tid; e < E; e += blockDim.x)
      if (keep[ei[e]]) supp[ej[e]] = 1;
    __syncthreads();
    for (int r = tid; r < TOPK; r += blockDim.x){
      uint8_t nk = (uint8_t)(1 - supp[r]);
      if (nk != keep[r]){ keep[r] = nk; changed = 1; }
    }
    __syncthreads();
    int ch = changed;          // uniform snapshot
    __syncthreads();           // all reads complete before next round's write
    if (!ch) break;            // uniform branch
  }
  // ---- compaction phase (keep[] stable behind the barriers above) ----
  int r0 = tid * 10;
  uint32_t cnt = 0;
  for (int u = 0; u < 10; ++u){ int r = r0 + u; if (r < TOPK) cnt += keep[r]; }
  ps[tid] = cnt;
  __syncthreads();
  for (int off = 1; off < 1024; off <<= 1){
    uint32_t v = 0;
    if (tid >= off) v = ps[tid - off];
    __syncthreads();
    if (tid >= off) ps[tid] += v;
    __syncthreads();
  }
  uint32_t totalK = ps[1023];
  uint32_t p = ps[tid] - cnt;
  for (int u = 0; u < 10; ++u){
    int r = r0 + u; if (r >= TOPK) break;
    if (keep[r]){
      if (p < SSEL){
        int o = b*SSEL + (int)p;
        out[o*4 + 0] = w->bd.bx4[b][r][0];
        out[o*4 + 1] = w->bd.bx4[b][r][1];
        out[o*4 + 2] = w->bd.bx4[b][r][2];
        out[o*4 + 3] = w->bd.bx4[b][r][3];
        out[BS*SSEL*4 + o] = w->bd.srtS[b][r];
        out[BS*SSEL*5 + o] = (float)w->bd.lab[b][r];
        out[BS*SSEL*6 + o] = (float)r;
      }
      ++p;
    }
  }
  for (int slot = tid; slot < SSEL; slot += 1024){
    if ((uint32_t)slot >= totalK){
      int o = b*SSEL + slot;
      out[o*4 + 0] = 0.0f; out[o*4 + 1] = 0.0f;
      out[o*4 + 2] = 0.0f; out[o*4 + 3] = 0.0f;
      out[BS*SSEL*4 + o] = 0.0f;
      out[BS*SSEL*5 + o] = -1.0f;
      out[BS*SSEL*6 + o] = -1.0f;
    }
  }
}

extern "C" void kernel_launch(void* const* d_in, const int* in_sizes, int n_in,
                              void* d_out, int out_size, void* d_ws, size_t ws_size,
                              hipStream_t stream){
  (void)in_sizes; (void)n_in; (void)out_size;
  if (ws_size < sizeof(WS)) return;   // ~5.3 MB scratch required
  const float4* logits = (const float4*)d_in[0];
  const float*  pboxes = (const float*)d_in[1];
  const float*  tsz    = (const float*)d_in[3];
  float* out = (float*)d_out;
  WS* w = (WS*)d_ws;

  (void)hipMemsetAsync(d_ws, 0, sizeof(WSHead), stream);
  k_hist1  <<<dim3(128, BS), 256, 0, stream>>>(logits, w);
  k_sel1   <<<BS, 1024, 0, stream>>>(w);
  k_hist2  <<<dim3(128, BS), 256, 0, stream>>>(logits, w);
  k_sel2   <<<BS, 1024, 0, stream>>>(w);
  k_compact<<<dim3(128, BS), 256, 0, stream>>>(logits, w);
  k_rankp  <<<dim3(CAP/IPB, CAP/SEGLEN, BS), 256, 0, stream>>>(w);
  k_pg     <<<dim3(CAP/256, BS), 256, 0, stream>>>(w, pboxes, tsz);
  k_cstart <<<BS, 1024, 0, stream>>>(w);
  k_os     <<<dim3(40, BS), 256, 0, stream>>>(w);
  k_edges  <<<dim3(40, BS), 256, 0, stream>>>(w);
  k_nmsout <<<BS, 1024, 0, stream>>>(w, out);
}